// Round 10
// baseline (195.265 us; speedup 1.0000x reference)
//
#include <hip/hip_runtime.h>
#include <math.h>

#define N_NODES 50000
#define N_EDGES 800000
#define NEG_SLOPE 0.2f
#define NB_BKT  ((N_NODES + 127) / 128)   // 391 dst-buckets of 128 nodes
#define BKT_CAP 3200                      // per-bucket total cap (mean ~2176)
#define P1_CHUNK 4096
#define NB_P1   ((N_EDGES + P1_CHUNK - 1) / P1_CHUNK)   // 196 chunks (random edges only)
#define NB_G1   ((N_NODES + 127) / 128)   // 391 gemm blocks
#define CELL_CAP 48                       // per (chunk,bucket) cell cap (Poisson mean 10.5)

typedef short bf16x8 __attribute__((ext_vector_type(8)));
typedef unsigned short u16x8 __attribute__((ext_vector_type(8)));
typedef float f32x4 __attribute__((ext_vector_type(4)));

static __device__ __forceinline__ float lrelu(float v) {
    return v > 0.0f ? v : NEG_SLOPE * v;
}

// round-to-nearest-even fp32 -> bf16
static __device__ __forceinline__ unsigned short f2bf(float f) {
    unsigned b = __float_as_uint(f);
    return (unsigned short)((b + 0x7fffu + ((b >> 16) & 1u)) >> 16);
}

static __device__ __forceinline__ float bflo(unsigned u) { return __uint_as_float(u << 16); }
static __device__ __forceinline__ float bfhi(unsigned u) { return __uint_as_float(u & 0xffff0000u); }

// LDS index (ushort units) for element (row, k) of a row*128 bf16 tile.
static __device__ __forceinline__ int swz(int row, int k) {
    return row * 128 + ((((k >> 3) ^ (row & 15)) << 3) | (k & 7));
}
// 64-wide variant for the gemm2 h2b repack
static __device__ __forceinline__ int swz64(int row, int c) {
    return row * 64 + ((((c >> 3) ^ (row & 7)) << 3) | (c & 7));
}

// -------- P1: deterministic cell-sliced binning of the 800K RANDOM edges.
// Self-loops never enter the binning (they are injected analytically in P2),
// so every cell is pure Poisson(10.5) and CELL_CAP=48 cannot overflow.
// Each block owns its cells exclusively -> no global atomics, no memset.
__global__ __launch_bounds__(256) void scatterP1_kernel(const int* __restrict__ ei,
                                                        int* __restrict__ cellcnt,
                                                        unsigned* __restrict__ cells) {
    __shared__ int cnt[NB_BKT];
    int tid = threadIdx.x;
    int c = blockIdx.x;
    for (int i = tid; i < NB_BKT; i += 256) cnt[i] = 0;
    __syncthreads();
    int cbase = c * P1_CHUNK;
    for (int i = tid; i < P1_CHUNK; i += 256) {
        int e = cbase + i;
        if (e >= N_EDGES) break;
        int s = ei[e];
        int d = ei[N_EDGES + e];
        int bk = d >> 7;
        int pos = atomicAdd(&cnt[bk], 1);
        if (pos < CELL_CAP)
            cells[(size_t)(c * NB_BKT + bk) * CELL_CAP + pos] =
                ((unsigned)s << 7) | (unsigned)(d & 127);
    }
    __syncthreads();
    for (int i = tid; i < NB_BKT; i += 256) {
        int v = cnt[i];
        cellcnt[c * NB_BKT + i] = v < CELL_CAP ? v : CELL_CAP;
    }
}

// -------- fused B: blocks [0,NB_BKT) = CSR build P2; [NB_BKT,..) = GEMM1.
// Both paths fit a 32 KB LDS union -> 4 blocks/CU, all 782 blocks co-resident;
// P2 (~15us) hides under GEMM1. Self-loop for each node is injected here.
// DETERMINISM (P2): final slot = rank of key within the node's segment; ties
// are bitwise-identical keys, so csr_src is a pure function of the input.
__global__ __launch_bounds__(256, 4) void fusedB_kernel(const float* __restrict__ x,
                                                        const float* __restrict__ W,
                                                        const float* __restrict__ a_src,
                                                        const float* __restrict__ a_dst,
                                                        unsigned short* __restrict__ h1b,
                                                        float* __restrict__ as_out,
                                                        float* __restrict__ ad_out,
                                                        const int* __restrict__ cellcnt,
                                                        const unsigned* __restrict__ cells,
                                                        int* __restrict__ offsets,
                                                        int* __restrict__ deg,
                                                        int* __restrict__ csr_src) {
    __shared__ __align__(16) unsigned char smem[32768];
    int tid = threadIdx.x;

    if (blockIdx.x < NB_BKT) {
        // ---------------- CSR build P2 path ----------------
        int* cnt   = (int*)smem;             // 256: node counts / alloc ptr
        int* scn   = (int*)(smem + 1024);    // 256: node inclusive scan
        int* sst   = (int*)(smem + 2048);    // 256: node segment starts
        int* cincl = (int*)(smem + 3072);    // 256: cell inclusive scan
        int* fkeys = (int*)(smem + 4096);                  // BKT_CAP flat keys
        int* lsrc  = (int*)(smem + 4096 + 4 * BKT_CAP);    // BKT_CAP segmented
        int t = tid;
        int b = blockIdx.x;
        int pbase = b * BKT_CAP;
        int node0 = b << 7;
        int nloc = N_NODES - node0; if (nloc > 128) nloc = 128;

        cnt[t] = (t < nloc) ? 1 : 0;     // self-loop pre-count
        cincl[t] = (t < NB_P1) ? cellcnt[t * NB_BKT + b] : 0;
        __syncthreads();
#pragma unroll
        for (int off = 1; off < 256; off <<= 1) {
            int u = (t >= off) ? cincl[t - off] : 0;
            __syncthreads();
            cincl[t] += u;
            __syncthreads();
        }
        int cntE = cincl[255];           // random edges in this bucket
        // flat-load random keys (binary search cell), histogram node counts
        for (int j = t; j < cntE; j += 256) {
            int lo = 0, hi = NB_P1 - 1;
            while (lo < hi) {
                int mid = (lo + hi) >> 1;
                if (cincl[mid] <= j) lo = mid + 1; else hi = mid;
            }
            int cb2 = lo ? cincl[lo - 1] : 0;
            int k = (int)cells[(size_t)(lo * NB_BKT + b) * CELL_CAP + (j - cb2)];
            fkeys[j] = k;
            atomicAdd(&cnt[k & 127], 1);
        }
        // inject self-loop keys (exclusive slots)
        if (t < nloc) fkeys[cntE + t] = ((node0 + t) << 7) | t;
        int cntE2 = cntE + nloc;
        __syncthreads();
        int v = cnt[t];
        scn[t] = v;
        __syncthreads();
#pragma unroll
        for (int off = 1; off < 256; off <<= 1) {
            int u = (t >= off) ? scn[t - off] : 0;
            __syncthreads();
            scn[t] += u;
            __syncthreads();
        }
        int lstart = scn[t] - v;
        sst[t] = lstart;
        cnt[t] = lstart;
        if (t < nloc) {
            offsets[node0 + t] = pbase + lstart;
            deg[node0 + t] = v;
        }
        __syncthreads();
        // place into segmented image
        for (int j = t; j < cntE2; j += 256) {
            int k = fkeys[j];
            int p = atomicAdd(&cnt[k & 127], 1);
            lsrc[p] = k;
        }
        __syncthreads();
        // deterministic rank-place, direct global write
        for (int j = t; j < cntE2; j += 256) {
            int w = lsrc[j];
            int dl = w & 127;
            int st = sst[dl];
            int en = scn[dl];
            int r = 0;
            for (int k = st; k < en; ++k) {
                int wk = lsrc[k];
                r += (wk < w) ? 1 : ((wk == w && k < j) ? 1 : 0);
            }
            csr_src[pbase + st + r] = (int)(((unsigned)w) >> 7);
        }
        return;
    }

    // ---------------- GEMM1 path (direct-global A, 32 KB W^T LDS) ----------
    unsigned short* wt = (unsigned short*)smem;   // 32 KB W^T (reused for repack)
    int r0 = (blockIdx.x - NB_BKT) * 128;

    {   // stage W^T
        int n = tid & 127;
        int c0 = (tid >> 7) * 8;
        for (int c = c0; c < c0 + 8; ++c) {
            int kb = c * 8;
            ushort4 lo, hi;
            lo.x = f2bf(W[(kb + 0) * 128 + n]);
            lo.y = f2bf(W[(kb + 1) * 128 + n]);
            lo.z = f2bf(W[(kb + 2) * 128 + n]);
            lo.w = f2bf(W[(kb + 3) * 128 + n]);
            hi.x = f2bf(W[(kb + 4) * 128 + n]);
            hi.y = f2bf(W[(kb + 5) * 128 + n]);
            hi.z = f2bf(W[(kb + 6) * 128 + n]);
            hi.w = f2bf(W[(kb + 7) * 128 + n]);
            int a = swz(n, kb);
            *(ushort4*)&wt[a] = lo;
            *(ushort4*)&wt[a + 4] = hi;
        }
    }
    __syncthreads();

    int wv = tid >> 6, lane = tid & 63, lm = lane & 15, quad = lane >> 4;
    int row0 = r0 + wv * 32 + lm;
    int row1 = row0 + 16;
    if (row0 > N_NODES - 1) row0 = N_NODES - 1;
    if (row1 > N_NODES - 1) row1 = N_NODES - 1;

    f32x4 acc[2][8];
#pragma unroll
    for (int m = 0; m < 2; ++m)
#pragma unroll
        for (int n = 0; n < 8; ++n) acc[m][n] = (f32x4){0.f, 0.f, 0.f, 0.f};

#pragma unroll
    for (int kc = 0; kc < 4; ++kc) {
        int kb = kc * 32 + quad * 8;
        float4 va0 = *(const float4*)&x[row0 * 128 + kb];
        float4 va1 = *(const float4*)&x[row0 * 128 + kb + 4];
        float4 vb0 = *(const float4*)&x[row1 * 128 + kb];
        float4 vb1 = *(const float4*)&x[row1 * 128 + kb + 4];
        bf16x8 a0, a1;
        a0[0] = (short)f2bf(va0.x); a0[1] = (short)f2bf(va0.y);
        a0[2] = (short)f2bf(va0.z); a0[3] = (short)f2bf(va0.w);
        a0[4] = (short)f2bf(va1.x); a0[5] = (short)f2bf(va1.y);
        a0[6] = (short)f2bf(va1.z); a0[7] = (short)f2bf(va1.w);
        a1[0] = (short)f2bf(vb0.x); a1[1] = (short)f2bf(vb0.y);
        a1[2] = (short)f2bf(vb0.z); a1[3] = (short)f2bf(vb0.w);
        a1[4] = (short)f2bf(vb1.x); a1[5] = (short)f2bf(vb1.y);
        a1[6] = (short)f2bf(vb1.z); a1[7] = (short)f2bf(vb1.w);
#pragma unroll
        for (int nt = 0; nt < 8; ++nt) {
            bf16x8 bfr = *(bf16x8*)&wt[swz(nt * 16 + lm, kb)];
            acc[0][nt] = __builtin_amdgcn_mfma_f32_16x16x32_bf16(a0, bfr, acc[0][nt], 0, 0, 0);
            acc[1][nt] = __builtin_amdgcn_mfma_f32_16x16x32_bf16(a1, bfr, acc[1][nt], 0, 0, 0);
        }
    }

    float asv[8], adv[8];
#pragma unroll
    for (int nt = 0; nt < 8; ++nt) {
        asv[nt] = a_src[nt * 16 + lm];
        adv[nt] = a_dst[nt * 16 + lm];
    }
#pragma unroll
    for (int mt = 0; mt < 2; ++mt) {
#pragma unroll
        for (int r = 0; r < 4; ++r) {
            float s0 = 0.f, s1 = 0.f, d0 = 0.f, d1 = 0.f;
#pragma unroll
            for (int nt = 0; nt < 4; ++nt) {
                s0 += acc[mt][nt][r] * asv[nt];
                d0 += acc[mt][nt][r] * adv[nt];
            }
#pragma unroll
            for (int nt = 4; nt < 8; ++nt) {
                s1 += acc[mt][nt][r] * asv[nt];
                d1 += acc[mt][nt][r] * adv[nt];
            }
#pragma unroll
            for (int m = 1; m < 16; m <<= 1) {
                s0 += __shfl_xor(s0, m, 64);
                s1 += __shfl_xor(s1, m, 64);
                d0 += __shfl_xor(d0, m, 64);
                d1 += __shfl_xor(d1, m, 64);
            }
            if (lm == 0) {
                int gr = r0 + wv * 32 + mt * 16 + quad * 4 + r;
                if (gr < N_NODES) {
                    as_out[gr * 2 + 0] = s0;
                    as_out[gr * 2 + 1] = s1;
                    ad_out[gr * 2 + 0] = d0;
                    ad_out[gr * 2 + 1] = d1;
                }
            }
        }
    }

    __syncthreads();   // all waves done reading wt; reuse it as output tile
#pragma unroll
    for (int mt = 0; mt < 2; ++mt) {
#pragma unroll
        for (int nt = 0; nt < 8; ++nt) {
#pragma unroll
            for (int r = 0; r < 4; ++r) {
                int lrow = wv * 32 + mt * 16 + quad * 4 + r;
                wt[swz(lrow, nt * 16 + lm)] = f2bf(acc[mt][nt][r]);
            }
        }
    }
    __syncthreads();
    {
        int lrow = tid >> 1;
        int cb = (tid & 1) * 64;
        int gr = r0 + lrow;
        if (gr < N_NODES) {
            unsigned short* dst = h1b + (size_t)gr * 128 + cb;
#pragma unroll
            for (int c = 0; c < 8; ++c)
                *(uint4*)(dst + c * 8) = *(uint4*)&wt[swz(lrow, cb + c * 8)];
        }
    }
}

// -------- GEMM 2 (bf16 MFMA, direct-global A) + fused alphas2 --------
__global__ __launch_bounds__(256, 4) void gemm2_kernel(const unsigned short* __restrict__ xb,
                                                       const float* __restrict__ W,
                                                       const float* __restrict__ a_src,
                                                       const float* __restrict__ a_dst,
                                                       unsigned short* __restrict__ h2b,
                                                       float* __restrict__ as_out,
                                                       float* __restrict__ ad_out) {
    __shared__ unsigned short wt[64 * 128];   // 16 KB W^T (reused for repack)
    int tid = threadIdx.x;
    int r0 = blockIdx.x * 128;

    {   // stage W^T: wt[n][k] = W[k][n], n in [0,64)
        int n = tid & 63;
        int c0 = (tid >> 6) * 4;
        for (int c = c0; c < c0 + 4; ++c) {
            int kb = c * 8;
            ushort4 lo, hi;
            lo.x = f2bf(W[(kb + 0) * 64 + n]);
            lo.y = f2bf(W[(kb + 1) * 64 + n]);
            lo.z = f2bf(W[(kb + 2) * 64 + n]);
            lo.w = f2bf(W[(kb + 3) * 64 + n]);
            hi.x = f2bf(W[(kb + 4) * 64 + n]);
            hi.y = f2bf(W[(kb + 5) * 64 + n]);
            hi.z = f2bf(W[(kb + 6) * 64 + n]);
            hi.w = f2bf(W[(kb + 7) * 64 + n]);
            int a = swz(n, kb);
            *(ushort4*)&wt[a] = lo;
            *(ushort4*)&wt[a + 4] = hi;
        }
    }
    __syncthreads();

    int wv = tid >> 6, lane = tid & 63, lm = lane & 15, quad = lane >> 4;
    int row0 = r0 + wv * 32 + lm;
    int row1 = row0 + 16;
    if (row0 > N_NODES - 1) row0 = N_NODES - 1;
    if (row1 > N_NODES - 1) row1 = N_NODES - 1;

    f32x4 acc[2][4];
#pragma unroll
    for (int m = 0; m < 2; ++m)
#pragma unroll
        for (int n = 0; n < 4; ++n) acc[m][n] = (f32x4){0.f, 0.f, 0.f, 0.f};

#pragma unroll
    for (int kc = 0; kc < 4; ++kc) {
        int kb = kc * 32 + quad * 8;
        bf16x8 a0 = *(const bf16x8*)&xb[row0 * 128 + kb];
        bf16x8 a1 = *(const bf16x8*)&xb[row1 * 128 + kb];
#pragma unroll
        for (int nt = 0; nt < 4; ++nt) {
            bf16x8 b = *(bf16x8*)&wt[swz(nt * 16 + lm, kb)];
            acc[0][nt] = __builtin_amdgcn_mfma_f32_16x16x32_bf16(a0, b, acc[0][nt], 0, 0, 0);
            acc[1][nt] = __builtin_amdgcn_mfma_f32_16x16x32_bf16(a1, b, acc[1][nt], 0, 0, 0);
        }
    }

    float asv[4], adv[4];
#pragma unroll
    for (int nt = 0; nt < 4; ++nt) {
        asv[nt] = a_src[nt * 16 + lm];
        adv[nt] = a_dst[nt * 16 + lm];
    }
#pragma unroll
    for (int mt = 0; mt < 2; ++mt) {
#pragma unroll
        for (int r = 0; r < 4; ++r) {
            float s0 = 0.f, d0 = 0.f;
#pragma unroll
            for (int nt = 0; nt < 4; ++nt) {
                s0 += acc[mt][nt][r] * asv[nt];
                d0 += acc[mt][nt][r] * adv[nt];
            }
#pragma unroll
            for (int m = 1; m < 16; m <<= 1) {
                s0 += __shfl_xor(s0, m, 64);
                d0 += __shfl_xor(d0, m, 64);
            }
            if (lm == 0) {
                int gr = r0 + wv * 32 + mt * 16 + quad * 4 + r;
                if (gr < N_NODES) {
                    as_out[gr] = s0;
                    ad_out[gr] = d0;
                }
            }
        }
    }

    __syncthreads();   // all waves done reading wt; reuse as 128x64 repack tile
#pragma unroll
    for (int mt = 0; mt < 2; ++mt) {
#pragma unroll
        for (int nt = 0; nt < 4; ++nt) {
#pragma unroll
            for (int r = 0; r < 4; ++r) {
                int lrow = wv * 32 + mt * 16 + quad * 4 + r;
                wt[swz64(lrow, nt * 16 + lm)] = f2bf(acc[mt][nt][r]);
            }
        }
    }
    __syncthreads();
    {
        int lrow = tid >> 1;
        int cb = (tid & 1) * 32;
        int gr = r0 + lrow;
        if (gr < N_NODES) {
            unsigned short* dst = h2b + (size_t)gr * 64 + cb;
#pragma unroll
            for (int c = 0; c < 4; ++c)
                *(uint4*)(dst + c * 8) = *(uint4*)&wt[swz64(lrow, cb + c * 8)];
        }
    }
}

// -------- layer 1 aggregate: 16-lane-group/edge, uint4 gather, 16 edges/iter.
// 4 batched independent loads per iteration (MLP=4, the property that made the
// R6 form fast; R5's failed variant had 1 load/iter). Group-partial sums are
// merged by a fixed 2-step xor butterfly -> deterministic.
__global__ void agg1_kernel(const unsigned short* __restrict__ h1b,
                            const float* __restrict__ as1,
                            const float* __restrict__ ad1, const float* __restrict__ b1,
                            const int* __restrict__ offsets, const int* __restrict__ deg,
                            const int* __restrict__ csr_src,
                            unsigned short* __restrict__ out1b) {
    int wid = (blockIdx.x * blockDim.x + threadIdx.x) >> 6;
    if (wid >= N_NODES) return;
    int lane = threadIdx.x & 63;
    int grp = lane >> 4;           // edge-slot group 0..3
    int cq = lane & 15;            // uint4 index within the 256B row
    bool head1 = (cq >= 8);        // features 64..127
    float da0 = ad1[wid * 2 + 0], da1 = ad1[wid * 2 + 1];
    int jb = offsets[wid], je = jb + deg[wid];
    float a[8];
#pragma unroll
    for (int i = 0; i < 8; ++i) a[i] = 0.f;
    float psum0 = 0.f, psum1 = 0.f;

    for (int chunk = jb; chunk < je; chunk += 64) {
        int j = chunk + lane;
        int s = 0; float w0 = 0.f, w1 = 0.f;
        if (j < je) {
            s = csr_src[j];
            float2 av = *(const float2*)&as1[s * 2];
            w0 = __expf(lrelu(av.x + da0));
            w1 = __expf(lrelu(av.y + da1));
        }
        psum0 += w0; psum1 += w1;
        int cnt = je - chunk; if (cnt > 64) cnt = 64;
        for (int k = 0; k < cnt; k += 16) {
            int e0 = k + grp, e1 = k + 4 + grp, e2 = k + 8 + grp, e3 = k + 12 + grp;
            int ss0 = __shfl(s, e0, 64);
            int ss1 = __shfl(s, e1, 64);
            int ss2 = __shfl(s, e2, 64);
            int ss3 = __shfl(s, e3, 64);
            uint4 u0 = ((const uint4*)(h1b + (size_t)ss0 * 128))[cq];
            uint4 u1 = ((const uint4*)(h1b + (size_t)ss1 * 128))[cq];
            uint4 u2 = ((const uint4*)(h1b + (size_t)ss2 * 128))[cq];
            uint4 u3 = ((const uint4*)(h1b + (size_t)ss3 * 128))[cq];
            float p0 = __shfl(w0, e0, 64), q0 = __shfl(w1, e0, 64);
            float p1 = __shfl(w0, e1, 64), q1 = __shfl(w1, e1, 64);
            float p2 = __shfl(w0, e2, 64), q2 = __shfl(w1, e2, 64);
            float p3 = __shfl(w0, e3, 64), q3 = __shfl(w1, e3, 64);
            float bw0 = head1 ? q0 : p0;
            float bw1 = head1 ? q1 : p1;
            float bw2 = head1 ? q2 : p2;
            float bw3 = head1 ? q3 : p3;
            a[0] += bw0 * bflo(u0.x); a[1] += bw0 * bfhi(u0.x);
            a[2] += bw0 * bflo(u0.y); a[3] += bw0 * bfhi(u0.y);
            a[4] += bw0 * bflo(u0.z); a[5] += bw0 * bfhi(u0.z);
            a[6] += bw0 * bflo(u0.w); a[7] += bw0 * bfhi(u0.w);
            a[0] += bw1 * bflo(u1.x); a[1] += bw1 * bfhi(u1.x);
            a[2] += bw1 * bflo(u1.y); a[3] += bw1 * bfhi(u1.y);
            a[4] += bw1 * bflo(u1.z); a[5] += bw1 * bfhi(u1.z);
            a[6] += bw1 * bflo(u1.w); a[7] += bw1 * bfhi(u1.w);
            a[0] += bw2 * bflo(u2.x); a[1] += bw2 * bfhi(u2.x);
            a[2] += bw2 * bflo(u2.y); a[3] += bw2 * bfhi(u2.y);
            a[4] += bw2 * bflo(u2.z); a[5] += bw2 * bfhi(u2.z);
            a[6] += bw2 * bflo(u2.w); a[7] += bw2 * bfhi(u2.w);
            a[0] += bw3 * bflo(u3.x); a[1] += bw3 * bfhi(u3.x);
            a[2] += bw3 * bflo(u3.y); a[3] += bw3 * bfhi(u3.y);
            a[4] += bw3 * bflo(u3.z); a[5] += bw3 * bfhi(u3.z);
            a[6] += bw3 * bflo(u3.w); a[7] += bw3 * bfhi(u3.w);
        }
    }
#pragma unroll
    for (int m = 1; m < 64; m <<= 1) {
        psum0 += __shfl_xor(psum0, m, 64);
        psum1 += __shfl_xor(psum1, m, 64);
    }
    // merge the 4 edge-group partials (fixed order)
#pragma unroll
    for (int i = 0; i < 8; ++i) {
        a[i] += __shfl_xor(a[i], 16, 64);
        a[i] += __shfl_xor(a[i], 32, 64);
    }
    if (lane < 16) {
        float inv = 1.f / (head1 ? psum1 : psum0);
        float4 bv0 = *(const float4*)&b1[cq * 8];
        float4 bv1 = *(const float4*)&b1[cq * 8 + 4];
        float v0 = a[0] * inv + bv0.x;
        float v1 = a[1] * inv + bv0.y;
        float v2 = a[2] * inv + bv0.z;
        float v3 = a[3] * inv + bv0.w;
        float v4 = a[4] * inv + bv1.x;
        float v5 = a[5] * inv + bv1.y;
        float v6 = a[6] * inv + bv1.z;
        float v7 = a[7] * inv + bv1.w;
        v0 = v0 > 0.f ? v0 : 0.f; v1 = v1 > 0.f ? v1 : 0.f;
        v2 = v2 > 0.f ? v2 : 0.f; v3 = v3 > 0.f ? v3 : 0.f;
        v4 = v4 > 0.f ? v4 : 0.f; v5 = v5 > 0.f ? v5 : 0.f;
        v6 = v6 > 0.f ? v6 : 0.f; v7 = v7 > 0.f ? v7 : 0.f;
        u16x8 pk;
        pk[0] = f2bf(v0); pk[1] = f2bf(v1); pk[2] = f2bf(v2); pk[3] = f2bf(v3);
        pk[4] = f2bf(v4); pk[5] = f2bf(v5); pk[6] = f2bf(v6); pk[7] = f2bf(v7);
        *(u16x8*)&out1b[(size_t)wid * 128 + cq * 8] = pk;
    }
}

// -------- layer 2 aggregate: 16-lane-group/edge, uint2 gather, 16 edges/iter.
// Single head -> no weight selects. Same MLP=4 batched-load structure.
__global__ void agg2_kernel(const unsigned short* __restrict__ h2b,
                            const float* __restrict__ as2,
                            const float* __restrict__ ad2, const float* __restrict__ b2,
                            const int* __restrict__ offsets, const int* __restrict__ deg,
                            const int* __restrict__ csr_src,
                            float* __restrict__ out) {
    int wid = (blockIdx.x * blockDim.x + threadIdx.x) >> 6;
    if (wid >= N_NODES) return;
    int lane = threadIdx.x & 63;
    int grp = lane >> 4;           // edge-slot group 0..3
    int cq = lane & 15;            // uint2 index within the 128B row
    float da = ad2[wid];
    int jb = offsets[wid], je = jb + deg[wid];
    float a[4];
#pragma unroll
    for (int i = 0; i < 4; ++i) a[i] = 0.f;
    float psum = 0.f;

    for (int chunk = jb; chunk < je; chunk += 64) {
        int j = chunk + lane;
        int s = 0; float w = 0.f;
        if (j < je) {
            s = csr_src[j];
            w = __expf(lrelu(as2[s] + da));
        }
        psum += w;
        int cnt = je - chunk; if (cnt > 64) cnt = 64;
        for (int k = 0; k < cnt; k += 16) {
            int e0 = k + grp, e1 = k + 4 + grp, e2 = k + 8 + grp, e3 = k + 12 + grp;
            int ss0 = __shfl(s, e0, 64);
            int ss1 = __shfl(s, e1, 64);
            int ss2 = __shfl(s, e2, 64);
            int ss3 = __shfl(s, e3, 64);
            uint2 u0 = ((const uint2*)(h2b + (size_t)ss0 * 64))[cq];
            uint2 u1 = ((const uint2*)(h2b + (size_t)ss1 * 64))[cq];
            uint2 u2 = ((const uint2*)(h2b + (size_t)ss2 * 64))[cq];
            uint2 u3 = ((const uint2*)(h2b + (size_t)ss3 * 64))[cq];
            float bw0 = __shfl(w, e0, 64);
            float bw1 = __shfl(w, e1, 64);
            float bw2 = __shfl(w, e2, 64);
            float bw3 = __shfl(w, e3, 64);
            a[0] += bw0 * bflo(u0.x); a[1] += bw0 * bfhi(u0.x);
            a[2] += bw0 * bflo(u0.y); a[3] += bw0 * bfhi(u0.y);
            a[0] += bw1 * bflo(u1.x); a[1] += bw1 * bfhi(u1.x);
            a[2] += bw1 * bflo(u1.y); a[3] += bw1 * bfhi(u1.y);
            a[0] += bw2 * bflo(u2.x); a[1] += bw2 * bfhi(u2.x);
            a[2] += bw2 * bflo(u2.y); a[3] += bw2 * bfhi(u2.y);
            a[0] += bw3 * bflo(u3.x); a[1] += bw3 * bfhi(u3.x);
            a[2] += bw3 * bflo(u3.y); a[3] += bw3 * bfhi(u3.y);
        }
    }
#pragma unroll
    for (int m = 1; m < 64; m <<= 1) psum += __shfl_xor(psum, m, 64);
#pragma unroll
    for (int i = 0; i < 4; ++i) {
        a[i] += __shfl_xor(a[i], 16, 64);
        a[i] += __shfl_xor(a[i], 32, 64);
    }
    if (lane < 16) {
        float inv = 1.f / psum;
        float4 bv = *(const float4*)&b2[cq * 4];
        float v0 = a[0] * inv + bv.x;
        float v1 = a[1] * inv + bv.y;
        float v2 = a[2] * inv + bv.z;
        float v3 = a[3] * inv + bv.w;
        v0 = 1.f / (1.f + __expf(-v0));
        v1 = 1.f / (1.f + __expf(-v1));
        v2 = 1.f / (1.f + __expf(-v2));
        v3 = 1.f / (1.f + __expf(-v3));
        *(float4*)&out[(size_t)wid * 64 + cq * 4] = make_float4(v0, v1, v2, v3);
    }
}

extern "C" void kernel_launch(void* const* d_in, const int* in_sizes, int n_in,
                              void* d_out, int out_size, void* d_ws, size_t ws_size,
                              hipStream_t stream) {
    const float* x     = (const float*)d_in[0];
    const int*   ei    = (const int*)d_in[1];
    const float* W1    = (const float*)d_in[2];
    const float* asrc1 = (const float*)d_in[3];
    const float* adst1 = (const float*)d_in[4];
    const float* b1    = (const float*)d_in[5];
    const float* W2    = (const float*)d_in[6];
    const float* asrc2 = (const float*)d_in[7];
    const float* adst2 = (const float*)d_in[8];
    const float* b2    = (const float*)d_in[9];
    float* out = (float*)d_out;

    float* ws = (float*)d_ws;
    size_t off = 0;
    float* as1  = ws + off; off += (size_t)N_NODES * 2;
    float* ad1  = ws + off; off += (size_t)N_NODES * 2;
    float* as2  = ws + off; off += (size_t)N_NODES;
    float* ad2  = ws + off; off += (size_t)N_NODES;
    unsigned short* h1b   = (unsigned short*)(ws + off); off += (size_t)N_NODES * 64;  // 128 bf16
    unsigned short* out1b = (unsigned short*)(ws + off); off += (size_t)N_NODES * 64;  // 128 bf16
    unsigned short* h2b   = (unsigned short*)(ws + off); off += (size_t)N_NODES * 32;  // 64 bf16
    int* offsets = (int*)(ws + off);
    int* deg     = offsets + N_NODES;
    int* csr_src = deg + N_NODES;                         // padded: NB_BKT*BKT_CAP
    int* cellcnt = csr_src + NB_BKT * BKT_CAP;            // NB_P1*NB_BKT ints
    unsigned* cells = (unsigned*)(cellcnt + NB_P1 * NB_BKT);  // NB_P1*NB_BKT*CELL_CAP

    scatterP1_kernel<<<NB_P1, 256, 0, stream>>>(ei, cellcnt, cells);
    fusedB_kernel<<<NB_BKT + NB_G1, 256, 0, stream>>>(x, W1, asrc1, adst1, h1b, as1, ad1,
                                                      cellcnt, cells, offsets, deg, csr_src);
    agg1_kernel<<<(N_NODES * 64 + 255) / 256, 256, 0, stream>>>(h1b, as1, ad1, b1, offsets, deg, csr_src, out1b);
    gemm2_kernel<<<NB_G1, 256, 0, stream>>>(out1b, W2, asrc2, adst2, h2b, as2, ad2);
    agg2_kernel<<<(N_NODES * 64 + 255) / 256, 256, 0, stream>>>(h2b, as2, ad2, b2, offsets, deg, csr_src, out);
}

// Round 11
// 193.959 us; speedup vs baseline: 1.0067x; 1.0067x over previous
//
#include <hip/hip_runtime.h>
#include <math.h>

#define N_NODES 50000
#define N_EDGES 800000
#define NEG_SLOPE 0.2f
#define NB_BKT  ((N_NODES + 127) / 128)   // 391 dst-buckets of 128 nodes
#define BKT_CAP 3200                      // per-bucket total cap (mean ~2176)
#define P1_CHUNK 4096
#define NB_P1   ((N_EDGES + P1_CHUNK - 1) / P1_CHUNK)   // 196 chunks (random edges only)
#define NB_G1   ((N_NODES + 127) / 128)   // 391 gemm blocks
#define CELL_CAP 48                       // per (chunk,bucket) cell cap (Poisson mean 10.5)

typedef short bf16x8 __attribute__((ext_vector_type(8)));
typedef float f32x4 __attribute__((ext_vector_type(4)));
typedef float f32x2 __attribute__((ext_vector_type(2)));

static __device__ __forceinline__ float lrelu(float v) {
    return v > 0.0f ? v : NEG_SLOPE * v;
}

// round-to-nearest-even fp32 -> bf16
static __device__ __forceinline__ unsigned short f2bf(float f) {
    unsigned b = __float_as_uint(f);
    return (unsigned short)((b + 0x7fffu + ((b >> 16) & 1u)) >> 16);
}

static __device__ __forceinline__ float bflo(unsigned u) { return __uint_as_float(u << 16); }
static __device__ __forceinline__ float bfhi(unsigned u) { return __uint_as_float(u & 0xffff0000u); }
// bf16 pair -> f32x2 (feeds v_pk_fma_f32)
static __device__ __forceinline__ f32x2 bfp(unsigned u) {
    f32x2 r; r[0] = bflo(u); r[1] = bfhi(u); return r;
}

// LDS index (ushort units) for element (row, k) of a row*128 bf16 tile.
static __device__ __forceinline__ int swz(int row, int k) {
    return row * 128 + ((((k >> 3) ^ (row & 15)) << 3) | (k & 7));
}
// 64-wide variant for the gemm2 h2b repack
static __device__ __forceinline__ int swz64(int row, int c) {
    return row * 64 + ((((c >> 3) ^ (row & 7)) << 3) | (c & 7));
}

// -------- P1: deterministic cell-sliced binning of the 800K RANDOM edges.
// Self-loops never enter the binning (they are injected analytically in P2),
// so every cell is pure Poisson(10.5) and CELL_CAP=48 cannot overflow.
// Each block owns its cells exclusively -> no global atomics, no memset.
__global__ __launch_bounds__(256) void scatterP1_kernel(const int* __restrict__ ei,
                                                        int* __restrict__ cellcnt,
                                                        unsigned* __restrict__ cells) {
    __shared__ int cnt[NB_BKT];
    int tid = threadIdx.x;
    int c = blockIdx.x;
    for (int i = tid; i < NB_BKT; i += 256) cnt[i] = 0;
    __syncthreads();
    int cbase = c * P1_CHUNK;
    for (int i = tid; i < P1_CHUNK; i += 256) {
        int e = cbase + i;
        if (e >= N_EDGES) break;
        int s = ei[e];
        int d = ei[N_EDGES + e];
        int bk = d >> 7;
        int pos = atomicAdd(&cnt[bk], 1);
        if (pos < CELL_CAP)
            cells[(size_t)(c * NB_BKT + bk) * CELL_CAP + pos] =
                ((unsigned)s << 7) | (unsigned)(d & 127);
    }
    __syncthreads();
    for (int i = tid; i < NB_BKT; i += 256) {
        int v = cnt[i];
        cellcnt[c * NB_BKT + i] = v < CELL_CAP ? v : CELL_CAP;
    }
}

// -------- fused B: blocks [0,NB_BKT) = CSR build P2; [NB_BKT,..) = GEMM1.
// Both paths fit a 32 KB LDS union -> 4 blocks/CU, all 782 blocks co-resident;
// P2 (~15us) hides under GEMM1. Self-loop for each node is injected here.
// DETERMINISM (P2): final slot = rank of key within the node's segment; ties
// are bitwise-identical keys, so csr_src is a pure function of the input.
__global__ __launch_bounds__(256, 4) void fusedB_kernel(const float* __restrict__ x,
                                                        const float* __restrict__ W,
                                                        const float* __restrict__ a_src,
                                                        const float* __restrict__ a_dst,
                                                        unsigned short* __restrict__ h1b,
                                                        float* __restrict__ as_out,
                                                        float* __restrict__ ad_out,
                                                        const int* __restrict__ cellcnt,
                                                        const unsigned* __restrict__ cells,
                                                        int* __restrict__ offsets,
                                                        int* __restrict__ deg,
                                                        int* __restrict__ csr_src) {
    __shared__ __align__(16) unsigned char smem[32768];
    int tid = threadIdx.x;

    if (blockIdx.x < NB_BKT) {
        // ---------------- CSR build P2 path ----------------
        int* cnt   = (int*)smem;             // 256: node counts / alloc ptr
        int* scn   = (int*)(smem + 1024);    // 256: node inclusive scan
        int* sst   = (int*)(smem + 2048);    // 256: node segment starts
        int* cincl = (int*)(smem + 3072);    // 256: cell inclusive scan
        int* fkeys = (int*)(smem + 4096);                  // BKT_CAP flat keys
        int* lsrc  = (int*)(smem + 4096 + 4 * BKT_CAP);    // BKT_CAP segmented
        int t = tid;
        int b = blockIdx.x;
        int pbase = b * BKT_CAP;
        int node0 = b << 7;
        int nloc = N_NODES - node0; if (nloc > 128) nloc = 128;

        cnt[t] = (t < nloc) ? 1 : 0;     // self-loop pre-count
        cincl[t] = (t < NB_P1) ? cellcnt[t * NB_BKT + b] : 0;
        __syncthreads();
#pragma unroll
        for (int off = 1; off < 256; off <<= 1) {
            int u = (t >= off) ? cincl[t - off] : 0;
            __syncthreads();
            cincl[t] += u;
            __syncthreads();
        }
        int cntE = cincl[255];           // random edges in this bucket
        // flat-load random keys (binary search cell), histogram node counts
        for (int j = t; j < cntE; j += 256) {
            int lo = 0, hi = NB_P1 - 1;
            while (lo < hi) {
                int mid = (lo + hi) >> 1;
                if (cincl[mid] <= j) lo = mid + 1; else hi = mid;
            }
            int cb2 = lo ? cincl[lo - 1] : 0;
            int k = (int)cells[(size_t)(lo * NB_BKT + b) * CELL_CAP + (j - cb2)];
            fkeys[j] = k;
            atomicAdd(&cnt[k & 127], 1);
        }
        // inject self-loop keys (exclusive slots)
        if (t < nloc) fkeys[cntE + t] = ((node0 + t) << 7) | t;
        int cntE2 = cntE + nloc;
        __syncthreads();
        int v = cnt[t];
        scn[t] = v;
        __syncthreads();
#pragma unroll
        for (int off = 1; off < 256; off <<= 1) {
            int u = (t >= off) ? scn[t - off] : 0;
            __syncthreads();
            scn[t] += u;
            __syncthreads();
        }
        int lstart = scn[t] - v;
        sst[t] = lstart;
        cnt[t] = lstart;
        if (t < nloc) {
            offsets[node0 + t] = pbase + lstart;
            deg[node0 + t] = v;
        }
        __syncthreads();
        // place into segmented image
        for (int j = t; j < cntE2; j += 256) {
            int k = fkeys[j];
            int p = atomicAdd(&cnt[k & 127], 1);
            lsrc[p] = k;
        }
        __syncthreads();
        // deterministic rank-place, direct global write
        for (int j = t; j < cntE2; j += 256) {
            int w = lsrc[j];
            int dl = w & 127;
            int st = sst[dl];
            int en = scn[dl];
            int r = 0;
            for (int k = st; k < en; ++k) {
                int wk = lsrc[k];
                r += (wk < w) ? 1 : ((wk == w && k < j) ? 1 : 0);
            }
            csr_src[pbase + st + r] = (int)(((unsigned)w) >> 7);
        }
        return;
    }

    // ---------------- GEMM1 path (direct-global A, 32 KB W^T LDS) ----------
    unsigned short* wt = (unsigned short*)smem;   // 32 KB W^T (reused for repack)
    int r0 = (blockIdx.x - NB_BKT) * 128;

    {   // stage W^T
        int n = tid & 127;
        int c0 = (tid >> 7) * 8;
        for (int c = c0; c < c0 + 8; ++c) {
            int kb = c * 8;
            ushort4 lo, hi;
            lo.x = f2bf(W[(kb + 0) * 128 + n]);
            lo.y = f2bf(W[(kb + 1) * 128 + n]);
            lo.z = f2bf(W[(kb + 2) * 128 + n]);
            lo.w = f2bf(W[(kb + 3) * 128 + n]);
            hi.x = f2bf(W[(kb + 4) * 128 + n]);
            hi.y = f2bf(W[(kb + 5) * 128 + n]);
            hi.z = f2bf(W[(kb + 6) * 128 + n]);
            hi.w = f2bf(W[(kb + 7) * 128 + n]);
            int a = swz(n, kb);
            *(ushort4*)&wt[a] = lo;
            *(ushort4*)&wt[a + 4] = hi;
        }
    }
    __syncthreads();

    int wv = tid >> 6, lane = tid & 63, lm = lane & 15, quad = lane >> 4;
    int row0 = r0 + wv * 32 + lm;
    int row1 = row0 + 16;
    if (row0 > N_NODES - 1) row0 = N_NODES - 1;
    if (row1 > N_NODES - 1) row1 = N_NODES - 1;

    f32x4 acc[2][8];
#pragma unroll
    for (int m = 0; m < 2; ++m)
#pragma unroll
        for (int n = 0; n < 8; ++n) acc[m][n] = (f32x4){0.f, 0.f, 0.f, 0.f};

#pragma unroll
    for (int kc = 0; kc < 4; ++kc) {
        int kb = kc * 32 + quad * 8;
        float4 va0 = *(const float4*)&x[row0 * 128 + kb];
        float4 va1 = *(const float4*)&x[row0 * 128 + kb + 4];
        float4 vb0 = *(const float4*)&x[row1 * 128 + kb];
        float4 vb1 = *(const float4*)&x[row1 * 128 + kb + 4];
        bf16x8 a0, a1;
        a0[0] = (short)f2bf(va0.x); a0[1] = (short)f2bf(va0.y);
        a0[2] = (short)f2bf(va0.z); a0[3] = (short)f2bf(va0.w);
        a0[4] = (short)f2bf(va1.x); a0[5] = (short)f2bf(va1.y);
        a0[6] = (short)f2bf(va1.z); a0[7] = (short)f2bf(va1.w);
        a1[0] = (short)f2bf(vb0.x); a1[1] = (short)f2bf(vb0.y);
        a1[2] = (short)f2bf(vb0.z); a1[3] = (short)f2bf(vb0.w);
        a1[4] = (short)f2bf(vb1.x); a1[5] = (short)f2bf(vb1.y);
        a1[6] = (short)f2bf(vb1.z); a1[7] = (short)f2bf(vb1.w);
#pragma unroll
        for (int nt = 0; nt < 8; ++nt) {
            bf16x8 bfr = *(bf16x8*)&wt[swz(nt * 16 + lm, kb)];
            acc[0][nt] = __builtin_amdgcn_mfma_f32_16x16x32_bf16(a0, bfr, acc[0][nt], 0, 0, 0);
            acc[1][nt] = __builtin_amdgcn_mfma_f32_16x16x32_bf16(a1, bfr, acc[1][nt], 0, 0, 0);
        }
    }

    float asv[8], adv[8];
#pragma unroll
    for (int nt = 0; nt < 8; ++nt) {
        asv[nt] = a_src[nt * 16 + lm];
        adv[nt] = a_dst[nt * 16 + lm];
    }
#pragma unroll
    for (int mt = 0; mt < 2; ++mt) {
#pragma unroll
        for (int r = 0; r < 4; ++r) {
            float s0 = 0.f, s1 = 0.f, d0 = 0.f, d1 = 0.f;
#pragma unroll
            for (int nt = 0; nt < 4; ++nt) {
                s0 += acc[mt][nt][r] * asv[nt];
                d0 += acc[mt][nt][r] * adv[nt];
            }
#pragma unroll
            for (int nt = 4; nt < 8; ++nt) {
                s1 += acc[mt][nt][r] * asv[nt];
                d1 += acc[mt][nt][r] * adv[nt];
            }
#pragma unroll
            for (int m = 1; m < 16; m <<= 1) {
                s0 += __shfl_xor(s0, m, 64);
                s1 += __shfl_xor(s1, m, 64);
                d0 += __shfl_xor(d0, m, 64);
                d1 += __shfl_xor(d1, m, 64);
            }
            if (lm == 0) {
                int gr = r0 + wv * 32 + mt * 16 + quad * 4 + r;
                if (gr < N_NODES) {
                    as_out[gr * 2 + 0] = s0;
                    as_out[gr * 2 + 1] = s1;
                    ad_out[gr * 2 + 0] = d0;
                    ad_out[gr * 2 + 1] = d1;
                }
            }
        }
    }

    __syncthreads();   // all waves done reading wt; reuse it as output tile
#pragma unroll
    for (int mt = 0; mt < 2; ++mt) {
#pragma unroll
        for (int nt = 0; nt < 8; ++nt) {
#pragma unroll
            for (int r = 0; r < 4; ++r) {
                int lrow = wv * 32 + mt * 16 + quad * 4 + r;
                wt[swz(lrow, nt * 16 + lm)] = f2bf(acc[mt][nt][r]);
            }
        }
    }
    __syncthreads();
    {
        int lrow = tid >> 1;
        int cb = (tid & 1) * 64;
        int gr = r0 + lrow;
        if (gr < N_NODES) {
            unsigned short* dst = h1b + (size_t)gr * 128 + cb;
#pragma unroll
            for (int c = 0; c < 8; ++c)
                *(uint4*)(dst + c * 8) = *(uint4*)&wt[swz(lrow, cb + c * 8)];
        }
    }
}

// -------- GEMM 2 (bf16 MFMA, direct-global A) + fused alphas2 --------
__global__ __launch_bounds__(256, 4) void gemm2_kernel(const unsigned short* __restrict__ xb,
                                                       const float* __restrict__ W,
                                                       const float* __restrict__ a_src,
                                                       const float* __restrict__ a_dst,
                                                       unsigned short* __restrict__ h2b,
                                                       float* __restrict__ as_out,
                                                       float* __restrict__ ad_out) {
    __shared__ unsigned short wt[64 * 128];   // 16 KB W^T (reused for repack)
    int tid = threadIdx.x;
    int r0 = blockIdx.x * 128;

    {   // stage W^T: wt[n][k] = W[k][n], n in [0,64)
        int n = tid & 63;
        int c0 = (tid >> 6) * 4;
        for (int c = c0; c < c0 + 4; ++c) {
            int kb = c * 8;
            ushort4 lo, hi;
            lo.x = f2bf(W[(kb + 0) * 64 + n]);
            lo.y = f2bf(W[(kb + 1) * 64 + n]);
            lo.z = f2bf(W[(kb + 2) * 64 + n]);
            lo.w = f2bf(W[(kb + 3) * 64 + n]);
            hi.x = f2bf(W[(kb + 4) * 64 + n]);
            hi.y = f2bf(W[(kb + 5) * 64 + n]);
            hi.z = f2bf(W[(kb + 6) * 64 + n]);
            hi.w = f2bf(W[(kb + 7) * 64 + n]);
            int a = swz(n, kb);
            *(ushort4*)&wt[a] = lo;
            *(ushort4*)&wt[a + 4] = hi;
        }
    }
    __syncthreads();

    int wv = tid >> 6, lane = tid & 63, lm = lane & 15, quad = lane >> 4;
    int row0 = r0 + wv * 32 + lm;
    int row1 = row0 + 16;
    if (row0 > N_NODES - 1) row0 = N_NODES - 1;
    if (row1 > N_NODES - 1) row1 = N_NODES - 1;

    f32x4 acc[2][4];
#pragma unroll
    for (int m = 0; m < 2; ++m)
#pragma unroll
        for (int n = 0; n < 4; ++n) acc[m][n] = (f32x4){0.f, 0.f, 0.f, 0.f};

#pragma unroll
    for (int kc = 0; kc < 4; ++kc) {
        int kb = kc * 32 + quad * 8;
        bf16x8 a0 = *(const bf16x8*)&xb[row0 * 128 + kb];
        bf16x8 a1 = *(const bf16x8*)&xb[row1 * 128 + kb];
#pragma unroll
        for (int nt = 0; nt < 4; ++nt) {
            bf16x8 b = *(bf16x8*)&wt[swz(nt * 16 + lm, kb)];
            acc[0][nt] = __builtin_amdgcn_mfma_f32_16x16x32_bf16(a0, b, acc[0][nt], 0, 0, 0);
            acc[1][nt] = __builtin_amdgcn_mfma_f32_16x16x32_bf16(a1, b, acc[1][nt], 0, 0, 0);
        }
    }

    float asv[4], adv[4];
#pragma unroll
    for (int nt = 0; nt < 4; ++nt) {
        asv[nt] = a_src[nt * 16 + lm];
        adv[nt] = a_dst[nt * 16 + lm];
    }
#pragma unroll
    for (int mt = 0; mt < 2; ++mt) {
#pragma unroll
        for (int r = 0; r < 4; ++r) {
            float s0 = 0.f, d0 = 0.f;
#pragma unroll
            for (int nt = 0; nt < 4; ++nt) {
                s0 += acc[mt][nt][r] * asv[nt];
                d0 += acc[mt][nt][r] * adv[nt];
            }
#pragma unroll
            for (int m = 1; m < 16; m <<= 1) {
                s0 += __shfl_xor(s0, m, 64);
                d0 += __shfl_xor(d0, m, 64);
            }
            if (lm == 0) {
                int gr = r0 + wv * 32 + mt * 16 + quad * 4 + r;
                if (gr < N_NODES) {
                    as_out[gr] = s0;
                    ad_out[gr] = d0;
                }
            }
        }
    }

    __syncthreads();   // all waves done reading wt; reuse as 128x64 repack tile
#pragma unroll
    for (int mt = 0; mt < 2; ++mt) {
#pragma unroll
        for (int nt = 0; nt < 4; ++nt) {
#pragma unroll
            for (int r = 0; r < 4; ++r) {
                int lrow = wv * 32 + mt * 16 + quad * 4 + r;
                wt[swz64(lrow, nt * 16 + lm)] = f2bf(acc[mt][nt][r]);
            }
        }
    }
    __syncthreads();
    {
        int lrow = tid >> 1;
        int cb = (tid & 1) * 32;
        int gr = r0 + lrow;
        if (gr < N_NODES) {
            unsigned short* dst = h2b + (size_t)gr * 64 + cb;
#pragma unroll
            for (int c = 0; c < 4; ++c)
                *(uint4*)(dst + c * 8) = *(uint4*)&wt[swz64(lrow, cb + c * 8)];
        }
    }
}

// -------- layer 1 aggregate: half-wave/edge, uint2 gather, 8 edges/iter.
// f32x2 accumulators -> v_pk_fma_f32 (halves FMA instruction count; agg is
// VALU-throughput-bound per R4 counters). Same summation order as R9.
__global__ void agg1_kernel(const unsigned short* __restrict__ h1b,
                            const float* __restrict__ as1,
                            const float* __restrict__ ad1, const float* __restrict__ b1,
                            const int* __restrict__ offsets, const int* __restrict__ deg,
                            const int* __restrict__ csr_src,
                            unsigned short* __restrict__ out1b) {
    int wid = (blockIdx.x * blockDim.x + threadIdx.x) >> 6;
    if (wid >= N_NODES) return;
    int lane = threadIdx.x & 63;
    int cl = lane & 31;
    int half = lane >> 5;
    bool head1 = (cl >= 16);
    float da0 = ad1[wid * 2 + 0], da1 = ad1[wid * 2 + 1];
    int jb = offsets[wid], je = jb + deg[wid];
    f32x2 A0 = (f32x2){0.f, 0.f}, A1 = (f32x2){0.f, 0.f};
    float psum0 = 0.f, psum1 = 0.f;

    for (int chunk = jb; chunk < je; chunk += 64) {
        int j = chunk + lane;
        int s = 0; float w0 = 0.f, w1 = 0.f;
        if (j < je) {
            s = csr_src[j];
            float2 av = *(const float2*)&as1[s * 2];
            w0 = __expf(lrelu(av.x + da0));
            w1 = __expf(lrelu(av.y + da1));
        }
        psum0 += w0; psum1 += w1;
        int cnt = je - chunk; if (cnt > 64) cnt = 64;
        for (int k = 0; k < cnt; k += 8) {
            int k0 = k + half, k1 = k + 2 + half, k2 = k + 4 + half, k3 = k + 6 + half;
            int ss0 = __shfl(s, k0, 64);
            int ss1 = __shfl(s, k1, 64);
            int ss2 = __shfl(s, k2, 64);
            int ss3 = __shfl(s, k3, 64);
            uint2 u0 = ((const uint2*)(h1b + (size_t)ss0 * 128))[cl];
            uint2 u1 = ((const uint2*)(h1b + (size_t)ss1 * 128))[cl];
            uint2 u2 = ((const uint2*)(h1b + (size_t)ss2 * 128))[cl];
            uint2 u3 = ((const uint2*)(h1b + (size_t)ss3 * 128))[cl];
            float p0 = __shfl(w0, k0, 64), q0 = __shfl(w1, k0, 64);
            float p1 = __shfl(w0, k1, 64), q1 = __shfl(w1, k1, 64);
            float p2 = __shfl(w0, k2, 64), q2 = __shfl(w1, k2, 64);
            float p3 = __shfl(w0, k3, 64), q3 = __shfl(w1, k3, 64);
            float bw0 = head1 ? q0 : p0;
            float bw1 = head1 ? q1 : p1;
            float bw2 = head1 ? q2 : p2;
            float bw3 = head1 ? q3 : p3;
            f32x2 W0 = (f32x2){bw0, bw0};
            f32x2 W1v = (f32x2){bw1, bw1};
            f32x2 W2v = (f32x2){bw2, bw2};
            f32x2 W3 = (f32x2){bw3, bw3};
            A0 += W0 * bfp(u0.x); A1 += W0 * bfp(u0.y);
            A0 += W1v * bfp(u1.x); A1 += W1v * bfp(u1.y);
            A0 += W2v * bfp(u2.x); A1 += W2v * bfp(u2.y);
            A0 += W3 * bfp(u3.x); A1 += W3 * bfp(u3.y);
        }
    }
    float a0 = A0[0], a1 = A0[1], a2 = A1[0], a3 = A1[1];
#pragma unroll
    for (int m = 1; m < 64; m <<= 1) {
        psum0 += __shfl_xor(psum0, m, 64);
        psum1 += __shfl_xor(psum1, m, 64);
    }
    float o0 = __shfl(a0, cl + 32, 64);
    float o1 = __shfl(a1, cl + 32, 64);
    float o2 = __shfl(a2, cl + 32, 64);
    float o3 = __shfl(a3, cl + 32, 64);
    if (lane < 32) {
        float inv = 1.f / (head1 ? psum1 : psum0);
        float4 bv = *(const float4*)&b1[cl * 4];
        float v0 = (a0 + o0) * inv + bv.x;
        float v1 = (a1 + o1) * inv + bv.y;
        float v2 = (a2 + o2) * inv + bv.z;
        float v3 = (a3 + o3) * inv + bv.w;
        v0 = v0 > 0.f ? v0 : 0.f;
        v1 = v1 > 0.f ? v1 : 0.f;
        v2 = v2 > 0.f ? v2 : 0.f;
        v3 = v3 > 0.f ? v3 : 0.f;
        ushort4 p;
        p.x = f2bf(v0); p.y = f2bf(v1); p.z = f2bf(v2); p.w = f2bf(v3);
        *(ushort4*)&out1b[(size_t)wid * 128 + cl * 4] = p;
    }
}

// -------- layer 2 aggregate: half-wave/edge, 8 edges/iter, f32x2 pk-fma ----
__global__ void agg2_kernel(const unsigned short* __restrict__ h2b,
                            const float* __restrict__ as2,
                            const float* __restrict__ ad2, const float* __restrict__ b2,
                            const int* __restrict__ offsets, const int* __restrict__ deg,
                            const int* __restrict__ csr_src,
                            float* __restrict__ out) {
    int wid = (blockIdx.x * blockDim.x + threadIdx.x) >> 6;
    if (wid >= N_NODES) return;
    int lane = threadIdx.x & 63;
    int cl = lane & 31;
    int half = lane >> 5;
    float da = ad2[wid];
    int jb = offsets[wid], je = jb + deg[wid];
    f32x2 A = (f32x2){0.f, 0.f};
    float psum = 0.f;

    for (int chunk = jb; chunk < je; chunk += 64) {
        int j = chunk + lane;
        int s = 0; float w = 0.f;
        if (j < je) {
            s = csr_src[j];
            w = __expf(lrelu(as2[s] + da));
        }
        psum += w;
        int cnt = je - chunk; if (cnt > 64) cnt = 64;
        for (int k = 0; k < cnt; k += 8) {
            int k0 = k + half, k1 = k + 2 + half, k2 = k + 4 + half, k3 = k + 6 + half;
            int ss0 = __shfl(s, k0, 64);
            int ss1 = __shfl(s, k1, 64);
            int ss2 = __shfl(s, k2, 64);
            int ss3 = __shfl(s, k3, 64);
            unsigned u0 = ((const unsigned*)(h2b + (size_t)ss0 * 64))[cl];
            unsigned u1 = ((const unsigned*)(h2b + (size_t)ss1 * 64))[cl];
            unsigned u2 = ((const unsigned*)(h2b + (size_t)ss2 * 64))[cl];
            unsigned u3 = ((const unsigned*)(h2b + (size_t)ss3 * 64))[cl];
            float bw0 = __shfl(w, k0, 64);
            float bw1 = __shfl(w, k1, 64);
            float bw2 = __shfl(w, k2, 64);
            float bw3 = __shfl(w, k3, 64);
            A += (f32x2){bw0, bw0} * bfp(u0);
            A += (f32x2){bw1, bw1} * bfp(u1);
            A += (f32x2){bw2, bw2} * bfp(u2);
            A += (f32x2){bw3, bw3} * bfp(u3);
        }
    }
    float acc0 = A[0], acc1 = A[1];
#pragma unroll
    for (int m = 1; m < 64; m <<= 1) psum += __shfl_xor(psum, m, 64);
    float o0 = __shfl(acc0, cl + 32, 64);
    float o1 = __shfl(acc1, cl + 32, 64);
    if (lane < 32) {
        float inv = 1.f / psum;
        float2 bv = *(const float2*)&b2[cl * 2];
        float v0 = (acc0 + o0) * inv + bv.x;
        float v1 = (acc1 + o1) * inv + bv.y;
        v0 = 1.f / (1.f + __expf(-v0));
        v1 = 1.f / (1.f + __expf(-v1));
        *(float2*)&out[(size_t)wid * 64 + cl * 2] = make_float2(v0, v1);
    }
}

extern "C" void kernel_launch(void* const* d_in, const int* in_sizes, int n_in,
                              void* d_out, int out_size, void* d_ws, size_t ws_size,
                              hipStream_t stream) {
    const float* x     = (const float*)d_in[0];
    const int*   ei    = (const int*)d_in[1];
    const float* W1    = (const float*)d_in[2];
    const float* asrc1 = (const float*)d_in[3];
    const float* adst1 = (const float*)d_in[4];
    const float* b1    = (const float*)d_in[5];
    const float* W2    = (const float*)d_in[6];
    const float* asrc2 = (const float*)d_in[7];
    const float* adst2 = (const float*)d_in[8];
    const float* b2    = (const float*)d_in[9];
    float* out = (float*)d_out;

    float* ws = (float*)d_ws;
    size_t off = 0;
    float* as1  = ws + off; off += (size_t)N_NODES * 2;
    float* ad1  = ws + off; off += (size_t)N_NODES * 2;
    float* as2  = ws + off; off += (size_t)N_NODES;
    float* ad2  = ws + off; off += (size_t)N_NODES;
    unsigned short* h1b   = (unsigned short*)(ws + off); off += (size_t)N_NODES * 64;  // 128 bf16
    unsigned short* out1b = (unsigned short*)(ws + off); off += (size_t)N_NODES * 64;  // 128 bf16
    unsigned short* h2b   = (unsigned short*)(ws + off); off += (size_t)N_NODES * 32;  // 64 bf16
    int* offsets = (int*)(ws + off);
    int* deg     = offsets + N_NODES;
    int* csr_src = deg + N_NODES;                         // padded: NB_BKT*BKT_CAP
    int* cellcnt = csr_src + NB_BKT * BKT_CAP;            // NB_P1*NB_BKT ints
    unsigned* cells = (unsigned*)(cellcnt + NB_P1 * NB_BKT);  // NB_P1*NB_BKT*CELL_CAP

    scatterP1_kernel<<<NB_P1, 256, 0, stream>>>(ei, cellcnt, cells);
    fusedB_kernel<<<NB_BKT + NB_G1, 256, 0, stream>>>(x, W1, asrc1, adst1, h1b, as1, ad1,
                                                      cellcnt, cells, offsets, deg, csr_src);
    agg1_kernel<<<(N_NODES * 64 + 255) / 256, 256, 0, stream>>>(h1b, as1, ad1, b1, offsets, deg, csr_src, out1b);
    gemm2_kernel<<<NB_G1, 256, 0, stream>>>(out1b, W2, asrc2, adst2, h2b, as2, ad2);
    agg2_kernel<<<(N_NODES * 64 + 255) / 256, 256, 0, stream>>>(h2b, as2, ad2, b2, offsets, deg, csr_src, out);
}

// Round 12
// 188.341 us; speedup vs baseline: 1.0368x; 1.0298x over previous
//
#include <hip/hip_runtime.h>
#include <math.h>

#define N_NODES 50000
#define NH (N_NODES / 2)
#define N_EDGES 800000
#define NEG_SLOPE 0.2f
#define NB_BKT  ((N_NODES + 127) / 128)   // 391 dst-buckets of 128 nodes
#define BKT_CAP 3200                      // per-bucket total cap (mean ~2176)
#define P1_CHUNK 4096
#define NB_P1   ((N_EDGES + P1_CHUNK - 1) / P1_CHUNK)   // 196 chunks (random edges only)
#define NB_G1   ((N_NODES + 127) / 128)   // 391 gemm blocks
#define CELL_CAP 48                       // per (chunk,bucket) cell cap (Poisson mean 10.5)

typedef short bf16x8 __attribute__((ext_vector_type(8)));
typedef float f32x4 __attribute__((ext_vector_type(4)));
typedef float f32x2 __attribute__((ext_vector_type(2)));

static __device__ __forceinline__ float lrelu(float v) {
    return v > 0.0f ? v : NEG_SLOPE * v;
}

// round-to-nearest-even fp32 -> bf16
static __device__ __forceinline__ unsigned short f2bf(float f) {
    unsigned b = __float_as_uint(f);
    return (unsigned short)((b + 0x7fffu + ((b >> 16) & 1u)) >> 16);
}

static __device__ __forceinline__ float bflo(unsigned u) { return __uint_as_float(u << 16); }
static __device__ __forceinline__ float bfhi(unsigned u) { return __uint_as_float(u & 0xffff0000u); }
static __device__ __forceinline__ f32x2 bfp(unsigned u) {
    f32x2 r; r[0] = bflo(u); r[1] = bfhi(u); return r;
}

// LDS index (ushort units) for element (row, k) of a row*128 bf16 tile.
static __device__ __forceinline__ int swz(int row, int k) {
    return row * 128 + ((((k >> 3) ^ (row & 15)) << 3) | (k & 7));
}
// 64-wide variant for the gemm2 h2b repack
static __device__ __forceinline__ int swz64(int row, int c) {
    return row * 64 + ((((c >> 3) ^ (row & 7)) << 3) | (c & 7));
}

// -------- P1: deterministic cell-sliced binning of the 800K RANDOM edges. ----
__global__ __launch_bounds__(256) void scatterP1_kernel(const int* __restrict__ ei,
                                                        int* __restrict__ cellcnt,
                                                        unsigned* __restrict__ cells) {
    __shared__ int cnt[NB_BKT];
    int tid = threadIdx.x;
    int c = blockIdx.x;
    for (int i = tid; i < NB_BKT; i += 256) cnt[i] = 0;
    __syncthreads();
    int cbase = c * P1_CHUNK;
    for (int i = tid; i < P1_CHUNK; i += 256) {
        int e = cbase + i;
        if (e >= N_EDGES) break;
        int s = ei[e];
        int d = ei[N_EDGES + e];
        int bk = d >> 7;
        int pos = atomicAdd(&cnt[bk], 1);
        if (pos < CELL_CAP)
            cells[(size_t)(c * NB_BKT + bk) * CELL_CAP + pos] =
                ((unsigned)s << 7) | (unsigned)(d & 127);
    }
    __syncthreads();
    for (int i = tid; i < NB_BKT; i += 256) {
        int v = cnt[i];
        cellcnt[c * NB_BKT + i] = v < CELL_CAP ? v : CELL_CAP;
    }
}

// -------- fused B: blocks [0,NB_BKT) = CSR build P2; [NB_BKT,..) = GEMM1. ----
__global__ __launch_bounds__(256, 4) void fusedB_kernel(const float* __restrict__ x,
                                                        const float* __restrict__ W,
                                                        const float* __restrict__ a_src,
                                                        const float* __restrict__ a_dst,
                                                        unsigned short* __restrict__ h1b,
                                                        float* __restrict__ as_out,
                                                        float* __restrict__ ad_out,
                                                        const int* __restrict__ cellcnt,
                                                        const unsigned* __restrict__ cells,
                                                        int* __restrict__ offsets,
                                                        int* __restrict__ deg,
                                                        int* __restrict__ csr_src) {
    __shared__ __align__(16) unsigned char smem[32768];
    int tid = threadIdx.x;

    if (blockIdx.x < NB_BKT) {
        // ---------------- CSR build P2 path ----------------
        int* cnt   = (int*)smem;
        int* scn   = (int*)(smem + 1024);
        int* sst   = (int*)(smem + 2048);
        int* cincl = (int*)(smem + 3072);
        int* fkeys = (int*)(smem + 4096);
        int* lsrc  = (int*)(smem + 4096 + 4 * BKT_CAP);
        int t = tid;
        int b = blockIdx.x;
        int pbase = b * BKT_CAP;
        int node0 = b << 7;
        int nloc = N_NODES - node0; if (nloc > 128) nloc = 128;

        cnt[t] = (t < nloc) ? 1 : 0;
        cincl[t] = (t < NB_P1) ? cellcnt[t * NB_BKT + b] : 0;
        __syncthreads();
#pragma unroll
        for (int off = 1; off < 256; off <<= 1) {
            int u = (t >= off) ? cincl[t - off] : 0;
            __syncthreads();
            cincl[t] += u;
            __syncthreads();
        }
        int cntE = cincl[255];
        for (int j = t; j < cntE; j += 256) {
            int lo = 0, hi = NB_P1 - 1;
            while (lo < hi) {
                int mid = (lo + hi) >> 1;
                if (cincl[mid] <= j) lo = mid + 1; else hi = mid;
            }
            int cb2 = lo ? cincl[lo - 1] : 0;
            int k = (int)cells[(size_t)(lo * NB_BKT + b) * CELL_CAP + (j - cb2)];
            fkeys[j] = k;
            atomicAdd(&cnt[k & 127], 1);
        }
        if (t < nloc) fkeys[cntE + t] = ((node0 + t) << 7) | t;
        int cntE2 = cntE + nloc;
        __syncthreads();
        int v = cnt[t];
        scn[t] = v;
        __syncthreads();
#pragma unroll
        for (int off = 1; off < 256; off <<= 1) {
            int u = (t >= off) ? scn[t - off] : 0;
            __syncthreads();
            scn[t] += u;
            __syncthreads();
        }
        int lstart = scn[t] - v;
        sst[t] = lstart;
        cnt[t] = lstart;
        if (t < nloc) {
            offsets[node0 + t] = pbase + lstart;
            deg[node0 + t] = v;
        }
        __syncthreads();
        for (int j = t; j < cntE2; j += 256) {
            int k = fkeys[j];
            int p = atomicAdd(&cnt[k & 127], 1);
            lsrc[p] = k;
        }
        __syncthreads();
        for (int j = t; j < cntE2; j += 256) {
            int w = lsrc[j];
            int dl = w & 127;
            int st = sst[dl];
            int en = scn[dl];
            int r = 0;
            for (int k = st; k < en; ++k) {
                int wk = lsrc[k];
                r += (wk < w) ? 1 : ((wk == w && k < j) ? 1 : 0);
            }
            csr_src[pbase + st + r] = (int)(((unsigned)w) >> 7);
        }
        return;
    }

    // ---------------- GEMM1 path (direct-global A, 32 KB W^T LDS) ----------
    unsigned short* wt = (unsigned short*)smem;
    int r0 = (blockIdx.x - NB_BKT) * 128;

    {   // stage W^T
        int n = tid & 127;
        int c0 = (tid >> 7) * 8;
        for (int c = c0; c < c0 + 8; ++c) {
            int kb = c * 8;
            ushort4 lo, hi;
            lo.x = f2bf(W[(kb + 0) * 128 + n]);
            lo.y = f2bf(W[(kb + 1) * 128 + n]);
            lo.z = f2bf(W[(kb + 2) * 128 + n]);
            lo.w = f2bf(W[(kb + 3) * 128 + n]);
            hi.x = f2bf(W[(kb + 4) * 128 + n]);
            hi.y = f2bf(W[(kb + 5) * 128 + n]);
            hi.z = f2bf(W[(kb + 6) * 128 + n]);
            hi.w = f2bf(W[(kb + 7) * 128 + n]);
            int a = swz(n, kb);
            *(ushort4*)&wt[a] = lo;
            *(ushort4*)&wt[a + 4] = hi;
        }
    }
    __syncthreads();

    int wv = tid >> 6, lane = tid & 63, lm = lane & 15, quad = lane >> 4;
    int row0 = r0 + wv * 32 + lm;
    int row1 = row0 + 16;
    if (row0 > N_NODES - 1) row0 = N_NODES - 1;
    if (row1 > N_NODES - 1) row1 = N_NODES - 1;

    f32x4 acc[2][8];
#pragma unroll
    for (int m = 0; m < 2; ++m)
#pragma unroll
        for (int n = 0; n < 8; ++n) acc[m][n] = (f32x4){0.f, 0.f, 0.f, 0.f};

#pragma unroll
    for (int kc = 0; kc < 4; ++kc) {
        int kb = kc * 32 + quad * 8;
        float4 va0 = *(const float4*)&x[row0 * 128 + kb];
        float4 va1 = *(const float4*)&x[row0 * 128 + kb + 4];
        float4 vb0 = *(const float4*)&x[row1 * 128 + kb];
        float4 vb1 = *(const float4*)&x[row1 * 128 + kb + 4];
        bf16x8 a0, a1;
        a0[0] = (short)f2bf(va0.x); a0[1] = (short)f2bf(va0.y);
        a0[2] = (short)f2bf(va0.z); a0[3] = (short)f2bf(va0.w);
        a0[4] = (short)f2bf(va1.x); a0[5] = (short)f2bf(va1.y);
        a0[6] = (short)f2bf(va1.z); a0[7] = (short)f2bf(va1.w);
        a1[0] = (short)f2bf(vb0.x); a1[1] = (short)f2bf(vb0.y);
        a1[2] = (short)f2bf(vb0.z); a1[3] = (short)f2bf(vb0.w);
        a1[4] = (short)f2bf(vb1.x); a1[5] = (short)f2bf(vb1.y);
        a1[6] = (short)f2bf(vb1.z); a1[7] = (short)f2bf(vb1.w);
#pragma unroll
        for (int nt = 0; nt < 8; ++nt) {
            bf16x8 bfr = *(bf16x8*)&wt[swz(nt * 16 + lm, kb)];
            acc[0][nt] = __builtin_amdgcn_mfma_f32_16x16x32_bf16(a0, bfr, acc[0][nt], 0, 0, 0);
            acc[1][nt] = __builtin_amdgcn_mfma_f32_16x16x32_bf16(a1, bfr, acc[1][nt], 0, 0, 0);
        }
    }

    float asv[8], adv[8];
#pragma unroll
    for (int nt = 0; nt < 8; ++nt) {
        asv[nt] = a_src[nt * 16 + lm];
        adv[nt] = a_dst[nt * 16 + lm];
    }
#pragma unroll
    for (int mt = 0; mt < 2; ++mt) {
#pragma unroll
        for (int r = 0; r < 4; ++r) {
            float s0 = 0.f, s1 = 0.f, d0 = 0.f, d1 = 0.f;
#pragma unroll
            for (int nt = 0; nt < 4; ++nt) {
                s0 += acc[mt][nt][r] * asv[nt];
                d0 += acc[mt][nt][r] * adv[nt];
            }
#pragma unroll
            for (int nt = 4; nt < 8; ++nt) {
                s1 += acc[mt][nt][r] * asv[nt];
                d1 += acc[mt][nt][r] * adv[nt];
            }
#pragma unroll
            for (int m = 1; m < 16; m <<= 1) {
                s0 += __shfl_xor(s0, m, 64);
                s1 += __shfl_xor(s1, m, 64);
                d0 += __shfl_xor(d0, m, 64);
                d1 += __shfl_xor(d1, m, 64);
            }
            if (lm == 0) {
                int gr = r0 + wv * 32 + mt * 16 + quad * 4 + r;
                if (gr < N_NODES) {
                    as_out[gr * 2 + 0] = s0;
                    as_out[gr * 2 + 1] = s1;
                    ad_out[gr * 2 + 0] = d0;
                    ad_out[gr * 2 + 1] = d1;
                }
            }
        }
    }

    __syncthreads();
#pragma unroll
    for (int mt = 0; mt < 2; ++mt) {
#pragma unroll
        for (int nt = 0; nt < 8; ++nt) {
#pragma unroll
            for (int r = 0; r < 4; ++r) {
                int lrow = wv * 32 + mt * 16 + quad * 4 + r;
                wt[swz(lrow, nt * 16 + lm)] = f2bf(acc[mt][nt][r]);
            }
        }
    }
    __syncthreads();
    {
        int lrow = tid >> 1;
        int cb = (tid & 1) * 64;
        int gr = r0 + lrow;
        if (gr < N_NODES) {
            unsigned short* dst = h1b + (size_t)gr * 128 + cb;
#pragma unroll
            for (int c = 0; c < 8; ++c)
                *(uint4*)(dst + c * 8) = *(uint4*)&wt[swz(lrow, cb + c * 8)];
        }
    }
}

// -------- GEMM 2 (bf16 MFMA, direct-global A) + fused alphas2 --------
__global__ __launch_bounds__(256, 4) void gemm2_kernel(const unsigned short* __restrict__ xb,
                                                       const float* __restrict__ W,
                                                       const float* __restrict__ a_src,
                                                       const float* __restrict__ a_dst,
                                                       unsigned short* __restrict__ h2b,
                                                       float* __restrict__ as_out,
                                                       float* __restrict__ ad_out) {
    __shared__ unsigned short wt[64 * 128];
    int tid = threadIdx.x;
    int r0 = blockIdx.x * 128;

    {
        int n = tid & 63;
        int c0 = (tid >> 6) * 4;
        for (int c = c0; c < c0 + 4; ++c) {
            int kb = c * 8;
            ushort4 lo, hi;
            lo.x = f2bf(W[(kb + 0) * 64 + n]);
            lo.y = f2bf(W[(kb + 1) * 64 + n]);
            lo.z = f2bf(W[(kb + 2) * 64 + n]);
            lo.w = f2bf(W[(kb + 3) * 64 + n]);
            hi.x = f2bf(W[(kb + 4) * 64 + n]);
            hi.y = f2bf(W[(kb + 5) * 64 + n]);
            hi.z = f2bf(W[(kb + 6) * 64 + n]);
            hi.w = f2bf(W[(kb + 7) * 64 + n]);
            int a = swz(n, kb);
            *(ushort4*)&wt[a] = lo;
            *(ushort4*)&wt[a + 4] = hi;
        }
    }
    __syncthreads();

    int wv = tid >> 6, lane = tid & 63, lm = lane & 15, quad = lane >> 4;
    int row0 = r0 + wv * 32 + lm;
    int row1 = row0 + 16;
    if (row0 > N_NODES - 1) row0 = N_NODES - 1;
    if (row1 > N_NODES - 1) row1 = N_NODES - 1;

    f32x4 acc[2][4];
#pragma unroll
    for (int m = 0; m < 2; ++m)
#pragma unroll
        for (int n = 0; n < 4; ++n) acc[m][n] = (f32x4){0.f, 0.f, 0.f, 0.f};

#pragma unroll
    for (int kc = 0; kc < 4; ++kc) {
        int kb = kc * 32 + quad * 8;
        bf16x8 a0 = *(const bf16x8*)&xb[row0 * 128 + kb];
        bf16x8 a1 = *(const bf16x8*)&xb[row1 * 128 + kb];
#pragma unroll
        for (int nt = 0; nt < 4; ++nt) {
            bf16x8 b = *(bf16x8*)&wt[swz(nt * 16 + lm, kb)];
            acc[0][nt] = __builtin_amdgcn_mfma_f32_16x16x32_bf16(a0, b, acc[0][nt], 0, 0, 0);
            acc[1][nt] = __builtin_amdgcn_mfma_f32_16x16x32_bf16(a1, b, acc[1][nt], 0, 0, 0);
        }
    }

    float asv[4], adv[4];
#pragma unroll
    for (int nt = 0; nt < 4; ++nt) {
        asv[nt] = a_src[nt * 16 + lm];
        adv[nt] = a_dst[nt * 16 + lm];
    }
#pragma unroll
    for (int mt = 0; mt < 2; ++mt) {
#pragma unroll
        for (int r = 0; r < 4; ++r) {
            float s0 = 0.f, d0 = 0.f;
#pragma unroll
            for (int nt = 0; nt < 4; ++nt) {
                s0 += acc[mt][nt][r] * asv[nt];
                d0 += acc[mt][nt][r] * adv[nt];
            }
#pragma unroll
            for (int m = 1; m < 16; m <<= 1) {
                s0 += __shfl_xor(s0, m, 64);
                d0 += __shfl_xor(d0, m, 64);
            }
            if (lm == 0) {
                int gr = r0 + wv * 32 + mt * 16 + quad * 4 + r;
                if (gr < N_NODES) {
                    as_out[gr] = s0;
                    ad_out[gr] = d0;
                }
            }
        }
    }

    __syncthreads();
#pragma unroll
    for (int mt = 0; mt < 2; ++mt) {
#pragma unroll
        for (int nt = 0; nt < 4; ++nt) {
#pragma unroll
            for (int r = 0; r < 4; ++r) {
                int lrow = wv * 32 + mt * 16 + quad * 4 + r;
                wt[swz64(lrow, nt * 16 + lm)] = f2bf(acc[mt][nt][r]);
            }
        }
    }
    __syncthreads();
    {
        int lrow = tid >> 1;
        int cb = (tid & 1) * 32;
        int gr = r0 + lrow;
        if (gr < N_NODES) {
            unsigned short* dst = h2b + (size_t)gr * 64 + cb;
#pragma unroll
            for (int c = 0; c < 4; ++c)
                *(uint4*)(dst + c * 8) = *(uint4*)&wt[swz64(lrow, cb + c * 8)];
        }
    }
}

// -------- layer 1 aggregate: DUAL-NODE wave (A=wv, B=wv+NH). Per-node work
// is latency-bound (~2500cy chain, VALU floor only ~12us chip-wide), so halve
// wave count and overlap B's prologue (csr/as1/exp chain) with A's gather.
// Per-node arithmetic order identical to R11 -> bitwise-identical output.
__global__ __launch_bounds__(256) void agg1_kernel(const unsigned short* __restrict__ h1b,
                            const float* __restrict__ as1,
                            const float* __restrict__ ad1, const float* __restrict__ b1,
                            const int* __restrict__ offsets, const int* __restrict__ deg,
                            const int* __restrict__ csr_src,
                            unsigned short* __restrict__ out1b) {
    int wv = (blockIdx.x * blockDim.x + threadIdx.x) >> 6;
    if (wv >= NH) return;
    int lane = threadIdx.x & 63;
    int cl = lane & 31;
    int half = lane >> 5;
    bool head1 = (cl >= 16);
    int widA = wv, widB = wv + NH;

    // metadata for both nodes (independent load chains)
    float2 daA = *(const float2*)&ad1[widA * 2];
    float2 daB = *(const float2*)&ad1[widB * 2];
    int jbA = offsets[widA], jeA = jbA + deg[widA];
    int jbB = offsets[widB], jeB = jbB + deg[widB];

    // preload first-chunk s + weights for BOTH nodes
    int jA = jbA + lane, jB = jbB + lane;
    int spA = 0, spB = 0;
    float wpA0 = 0.f, wpA1 = 0.f, wpB0 = 0.f, wpB1 = 0.f;
    if (jA < jeA) spA = csr_src[jA];
    if (jB < jeB) spB = csr_src[jB];
    if (jA < jeA) {
        float2 av = *(const float2*)&as1[spA * 2];
        wpA0 = __expf(lrelu(av.x + daA.x));
        wpA1 = __expf(lrelu(av.y + daA.y));
    }
    if (jB < jeB) {
        float2 av = *(const float2*)&as1[spB * 2];
        wpB0 = __expf(lrelu(av.x + daB.x));
        wpB1 = __expf(lrelu(av.y + daB.y));
    }

    f32x2 A0A = (f32x2){0.f, 0.f}, A1A = (f32x2){0.f, 0.f};
    f32x2 A0B = (f32x2){0.f, 0.f}, A1B = (f32x2){0.f, 0.f};
    float psA0 = 0.f, psA1 = 0.f, psB0 = 0.f, psB1 = 0.f;

    // ---- node A ----
    for (int chunk = jbA; chunk < jeA; chunk += 64) {
        int s; float w0, w1;
        if (chunk == jbA) { s = spA; w0 = wpA0; w1 = wpA1; }
        else {
            int j = chunk + lane; s = 0; w0 = 0.f; w1 = 0.f;
            if (j < jeA) {
                s = csr_src[j];
                float2 av = *(const float2*)&as1[s * 2];
                w0 = __expf(lrelu(av.x + daA.x));
                w1 = __expf(lrelu(av.y + daA.y));
            }
        }
        psA0 += w0; psA1 += w1;
        int cnt = jeA - chunk; if (cnt > 64) cnt = 64;
        for (int k = 0; k < cnt; k += 8) {
            int k0 = k + half, k1 = k + 2 + half, k2 = k + 4 + half, k3 = k + 6 + half;
            int ss0 = __shfl(s, k0, 64);
            int ss1 = __shfl(s, k1, 64);
            int ss2 = __shfl(s, k2, 64);
            int ss3 = __shfl(s, k3, 64);
            uint2 u0 = ((const uint2*)(h1b + (size_t)ss0 * 128))[cl];
            uint2 u1 = ((const uint2*)(h1b + (size_t)ss1 * 128))[cl];
            uint2 u2 = ((const uint2*)(h1b + (size_t)ss2 * 128))[cl];
            uint2 u3 = ((const uint2*)(h1b + (size_t)ss3 * 128))[cl];
            float p0 = __shfl(w0, k0, 64), q0 = __shfl(w1, k0, 64);
            float p1 = __shfl(w0, k1, 64), q1 = __shfl(w1, k1, 64);
            float p2 = __shfl(w0, k2, 64), q2 = __shfl(w1, k2, 64);
            float p3 = __shfl(w0, k3, 64), q3 = __shfl(w1, k3, 64);
            float bw0 = head1 ? q0 : p0;
            float bw1 = head1 ? q1 : p1;
            float bw2 = head1 ? q2 : p2;
            float bw3 = head1 ? q3 : p3;
            A0A += (f32x2){bw0, bw0} * bfp(u0.x); A1A += (f32x2){bw0, bw0} * bfp(u0.y);
            A0A += (f32x2){bw1, bw1} * bfp(u1.x); A1A += (f32x2){bw1, bw1} * bfp(u1.y);
            A0A += (f32x2){bw2, bw2} * bfp(u2.x); A1A += (f32x2){bw2, bw2} * bfp(u2.y);
            A0A += (f32x2){bw3, bw3} * bfp(u3.x); A1A += (f32x2){bw3, bw3} * bfp(u3.y);
        }
    }

    // ---- node B ----
    for (int chunk = jbB; chunk < jeB; chunk += 64) {
        int s; float w0, w1;
        if (chunk == jbB) { s = spB; w0 = wpB0; w1 = wpB1; }
        else {
            int j = chunk + lane; s = 0; w0 = 0.f; w1 = 0.f;
            if (j < jeB) {
                s = csr_src[j];
                float2 av = *(const float2*)&as1[s * 2];
                w0 = __expf(lrelu(av.x + daB.x));
                w1 = __expf(lrelu(av.y + daB.y));
            }
        }
        psB0 += w0; psB1 += w1;
        int cnt = jeB - chunk; if (cnt > 64) cnt = 64;
        for (int k = 0; k < cnt; k += 8) {
            int k0 = k + half, k1 = k + 2 + half, k2 = k + 4 + half, k3 = k + 6 + half;
            int ss0 = __shfl(s, k0, 64);
            int ss1 = __shfl(s, k1, 64);
            int ss2 = __shfl(s, k2, 64);
            int ss3 = __shfl(s, k3, 64);
            uint2 u0 = ((const uint2*)(h1b + (size_t)ss0 * 128))[cl];
            uint2 u1 = ((const uint2*)(h1b + (size_t)ss1 * 128))[cl];
            uint2 u2 = ((const uint2*)(h1b + (size_t)ss2 * 128))[cl];
            uint2 u3 = ((const uint2*)(h1b + (size_t)ss3 * 128))[cl];
            float p0 = __shfl(w0, k0, 64), q0 = __shfl(w1, k0, 64);
            float p1 = __shfl(w0, k1, 64), q1 = __shfl(w1, k1, 64);
            float p2 = __shfl(w0, k2, 64), q2 = __shfl(w1, k2, 64);
            float p3 = __shfl(w0, k3, 64), q3 = __shfl(w1, k3, 64);
            float bw0 = head1 ? q0 : p0;
            float bw1 = head1 ? q1 : p1;
            float bw2 = head1 ? q2 : p2;
            float bw3 = head1 ? q3 : p3;
            A0B += (f32x2){bw0, bw0} * bfp(u0.x); A1B += (f32x2){bw0, bw0} * bfp(u0.y);
            A0B += (f32x2){bw1, bw1} * bfp(u1.x); A1B += (f32x2){bw1, bw1} * bfp(u1.y);
            A0B += (f32x2){bw2, bw2} * bfp(u2.x); A1B += (f32x2){bw2, bw2} * bfp(u2.y);
            A0B += (f32x2){bw3, bw3} * bfp(u3.x); A1B += (f32x2){bw3, bw3} * bfp(u3.y);
        }
    }

    // ---- epilogues (A and B butterflies interleave) ----
#pragma unroll
    for (int m = 1; m < 64; m <<= 1) {
        psA0 += __shfl_xor(psA0, m, 64);
        psA1 += __shfl_xor(psA1, m, 64);
        psB0 += __shfl_xor(psB0, m, 64);
        psB1 += __shfl_xor(psB1, m, 64);
    }
    float aA0 = A0A[0], aA1 = A0A[1], aA2 = A1A[0], aA3 = A1A[1];
    float aB0 = A0B[0], aB1 = A0B[1], aB2 = A1B[0], aB3 = A1B[1];
    float oA0 = __shfl(aA0, cl + 32, 64);
    float oA1 = __shfl(aA1, cl + 32, 64);
    float oA2 = __shfl(aA2, cl + 32, 64);
    float oA3 = __shfl(aA3, cl + 32, 64);
    float oB0 = __shfl(aB0, cl + 32, 64);
    float oB1 = __shfl(aB1, cl + 32, 64);
    float oB2 = __shfl(aB2, cl + 32, 64);
    float oB3 = __shfl(aB3, cl + 32, 64);
    if (lane < 32) {
        float4 bv = *(const float4*)&b1[cl * 4];
        {
            float inv = 1.f / (head1 ? psA1 : psA0);
            float v0 = (aA0 + oA0) * inv + bv.x;
            float v1 = (aA1 + oA1) * inv + bv.y;
            float v2 = (aA2 + oA2) * inv + bv.z;
            float v3 = (aA3 + oA3) * inv + bv.w;
            v0 = v0 > 0.f ? v0 : 0.f;
            v1 = v1 > 0.f ? v1 : 0.f;
            v2 = v2 > 0.f ? v2 : 0.f;
            v3 = v3 > 0.f ? v3 : 0.f;
            ushort4 p;
            p.x = f2bf(v0); p.y = f2bf(v1); p.z = f2bf(v2); p.w = f2bf(v3);
            *(ushort4*)&out1b[(size_t)widA * 128 + cl * 4] = p;
        }
        {
            float inv = 1.f / (head1 ? psB1 : psB0);
            float v0 = (aB0 + oB0) * inv + bv.x;
            float v1 = (aB1 + oB1) * inv + bv.y;
            float v2 = (aB2 + oB2) * inv + bv.z;
            float v3 = (aB3 + oB3) * inv + bv.w;
            v0 = v0 > 0.f ? v0 : 0.f;
            v1 = v1 > 0.f ? v1 : 0.f;
            v2 = v2 > 0.f ? v2 : 0.f;
            v3 = v3 > 0.f ? v3 : 0.f;
            ushort4 p;
            p.x = f2bf(v0); p.y = f2bf(v1); p.z = f2bf(v2); p.w = f2bf(v3);
            *(ushort4*)&out1b[(size_t)widB * 128 + cl * 4] = p;
        }
    }
}

// -------- layer 2 aggregate: DUAL-NODE wave, same rationale as agg1 --------
__global__ __launch_bounds__(256) void agg2_kernel(const unsigned short* __restrict__ h2b,
                            const float* __restrict__ as2,
                            const float* __restrict__ ad2, const float* __restrict__ b2,
                            const int* __restrict__ offsets, const int* __restrict__ deg,
                            const int* __restrict__ csr_src,
                            float* __restrict__ out) {
    int wv = (blockIdx.x * blockDim.x + threadIdx.x) >> 6;
    if (wv >= NH) return;
    int lane = threadIdx.x & 63;
    int cl = lane & 31;
    int half = lane >> 5;
    int widA = wv, widB = wv + NH;

    float daA = ad2[widA], daB = ad2[widB];
    int jbA = offsets[widA], jeA = jbA + deg[widA];
    int jbB = offsets[widB], jeB = jbB + deg[widB];

    int jA = jbA + lane, jB = jbB + lane;
    int spA = 0, spB = 0;
    float wpA = 0.f, wpB = 0.f;
    if (jA < jeA) spA = csr_src[jA];
    if (jB < jeB) spB = csr_src[jB];
    if (jA < jeA) wpA = __expf(lrelu(as2[spA] + daA));
    if (jB < jeB) wpB = __expf(lrelu(as2[spB] + daB));

    f32x2 AA = (f32x2){0.f, 0.f}, AB = (f32x2){0.f, 0.f};
    float psA = 0.f, psB = 0.f;

    // ---- node A ----
    for (int chunk = jbA; chunk < jeA; chunk += 64) {
        int s; float w;
        if (chunk == jbA) { s = spA; w = wpA; }
        else {
            int j = chunk + lane; s = 0; w = 0.f;
            if (j < jeA) { s = csr_src[j]; w = __expf(lrelu(as2[s] + daA)); }
        }
        psA += w;
        int cnt = jeA - chunk; if (cnt > 64) cnt = 64;
        for (int k = 0; k < cnt; k += 8) {
            int k0 = k + half, k1 = k + 2 + half, k2 = k + 4 + half, k3 = k + 6 + half;
            int ss0 = __shfl(s, k0, 64);
            int ss1 = __shfl(s, k1, 64);
            int ss2 = __shfl(s, k2, 64);
            int ss3 = __shfl(s, k3, 64);
            unsigned u0 = ((const unsigned*)(h2b + (size_t)ss0 * 64))[cl];
            unsigned u1 = ((const unsigned*)(h2b + (size_t)ss1 * 64))[cl];
            unsigned u2 = ((const unsigned*)(h2b + (size_t)ss2 * 64))[cl];
            unsigned u3 = ((const unsigned*)(h2b + (size_t)ss3 * 64))[cl];
            float bw0 = __shfl(w, k0, 64);
            float bw1 = __shfl(w, k1, 64);
            float bw2 = __shfl(w, k2, 64);
            float bw3 = __shfl(w, k3, 64);
            AA += (f32x2){bw0, bw0} * bfp(u0);
            AA += (f32x2){bw1, bw1} * bfp(u1);
            AA += (f32x2){bw2, bw2} * bfp(u2);
            AA += (f32x2){bw3, bw3} * bfp(u3);
        }
    }

    // ---- node B ----
    for (int chunk = jbB; chunk < jeB; chunk += 64) {
        int s; float w;
        if (chunk == jbB) { s = spB; w = wpB; }
        else {
            int j = chunk + lane; s = 0; w = 0.f;
            if (j < jeB) { s = csr_src[j]; w = __expf(lrelu(as2[s] + daB)); }
        }
        psB += w;
        int cnt = jeB - chunk; if (cnt > 64) cnt = 64;
        for (int k = 0; k < cnt; k += 8) {
            int k0 = k + half, k1 = k + 2 + half, k2 = k + 4 + half, k3 = k + 6 + half;
            int ss0 = __shfl(s, k0, 64);
            int ss1 = __shfl(s, k1, 64);
            int ss2 = __shfl(s, k2, 64);
            int ss3 = __shfl(s, k3, 64);
            unsigned u0 = ((const unsigned*)(h2b + (size_t)ss0 * 64))[cl];
            unsigned u1 = ((const unsigned*)(h2b + (size_t)ss1 * 64))[cl];
            unsigned u2 = ((const unsigned*)(h2b + (size_t)ss2 * 64))[cl];
            unsigned u3 = ((const unsigned*)(h2b + (size_t)ss3 * 64))[cl];
            float bw0 = __shfl(w, k0, 64);
            float bw1 = __shfl(w, k1, 64);
            float bw2 = __shfl(w, k2, 64);
            float bw3 = __shfl(w, k3, 64);
            AB += (f32x2){bw0, bw0} * bfp(u0);
            AB += (f32x2){bw1, bw1} * bfp(u1);
            AB += (f32x2){bw2, bw2} * bfp(u2);
            AB += (f32x2){bw3, bw3} * bfp(u3);
        }
    }

#pragma unroll
    for (int m = 1; m < 64; m <<= 1) {
        psA += __shfl_xor(psA, m, 64);
        psB += __shfl_xor(psB, m, 64);
    }
    float aA0 = AA[0], aA1 = AA[1], aB0 = AB[0], aB1 = AB[1];
    float oA0 = __shfl(aA0, cl + 32, 64);
    float oA1 = __shfl(aA1, cl + 32, 64);
    float oB0 = __shfl(aB0, cl + 32, 64);
    float oB1 = __shfl(aB1, cl + 32, 64);
    if (lane < 32) {
        float2 bv = *(const float2*)&b2[cl * 2];
        {
            float inv = 1.f / psA;
            float v0 = (aA0 + oA0) * inv + bv.x;
            float v1 = (aA1 + oA1) * inv + bv.y;
            v0 = 1.f / (1.f + __expf(-v0));
            v1 = 1.f / (1.f + __expf(-v1));
            *(float2*)&out[(size_t)widA * 64 + cl * 2] = make_float2(v0, v1);
        }
        {
            float inv = 1.f / psB;
            float v0 = (aB0 + oB0) * inv + bv.x;
            float v1 = (aB1 + oB1) * inv + bv.y;
            v0 = 1.f / (1.f + __expf(-v0));
            v1 = 1.f / (1.f + __expf(-v1));
            *(float2*)&out[(size_t)widB * 64 + cl * 2] = make_float2(v0, v1);
        }
    }
}

extern "C" void kernel_launch(void* const* d_in, const int* in_sizes, int n_in,
                              void* d_out, int out_size, void* d_ws, size_t ws_size,
                              hipStream_t stream) {
    const float* x     = (const float*)d_in[0];
    const int*   ei    = (const int*)d_in[1];
    const float* W1    = (const float*)d_in[2];
    const float* asrc1 = (const float*)d_in[3];
    const float* adst1 = (const float*)d_in[4];
    const float* b1    = (const float*)d_in[5];
    const float* W2    = (const float*)d_in[6];
    const float* asrc2 = (const float*)d_in[7];
    const float* adst2 = (const float*)d_in[8];
    const float* b2    = (const float*)d_in[9];
    float* out = (float*)d_out;

    float* ws = (float*)d_ws;
    size_t off = 0;
    float* as1  = ws + off; off += (size_t)N_NODES * 2;
    float* ad1  = ws + off; off += (size_t)N_NODES * 2;
    float* as2  = ws + off; off += (size_t)N_NODES;
    float* ad2  = ws + off; off += (size_t)N_NODES;
    unsigned short* h1b   = (unsigned short*)(ws + off); off += (size_t)N_NODES * 64;  // 128 bf16
    unsigned short* out1b = (unsigned short*)(ws + off); off += (size_t)N_NODES * 64;  // 128 bf16
    unsigned short* h2b   = (unsigned short*)(ws + off); off += (size_t)N_NODES * 32;  // 64 bf16
    int* offsets = (int*)(ws + off);
    int* deg     = offsets + N_NODES;
    int* csr_src = deg + N_NODES;                         // padded: NB_BKT*BKT_CAP
    int* cellcnt = csr_src + NB_BKT * BKT_CAP;            // NB_P1*NB_BKT ints
    unsigned* cells = (unsigned*)(cellcnt + NB_P1 * NB_BKT);  // NB_P1*NB_BKT*CELL_CAP

    scatterP1_kernel<<<NB_P1, 256, 0, stream>>>(ei, cellcnt, cells);
    fusedB_kernel<<<NB_BKT + NB_G1, 256, 0, stream>>>(x, W1, asrc1, adst1, h1b, as1, ad1,
                                                      cellcnt, cells, offsets, deg, csr_src);
    agg1_kernel<<<(NH * 64 + 255) / 256, 256, 0, stream>>>(h1b, as1, ad1, b1, offsets, deg, csr_src, out1b);
    gemm2_kernel<<<NB_G1, 256, 0, stream>>>(out1b, W2, asrc2, adst2, h2b, as2, ad2);
    agg2_kernel<<<(NH * 64 + 255) / 256, 256, 0, stream>>>(h2b, as2, ad2, b2, offsets, deg, csr_src, out);
}